// Round 5
// baseline (1172.020 us; speedup 1.0000x reference)
//
#include <hip/hip_runtime.h>
#include <hip/hip_bf16.h>

typedef unsigned short u16;
typedef __attribute__((ext_vector_type(8))) short short8;
typedef __attribute__((ext_vector_type(4))) short short4v;
typedef __attribute__((ext_vector_type(4))) float f32x4;

__device__ __forceinline__ u16 f2bf(float f){
  __hip_bfloat16 h = __float2bfloat16(f);
  return *reinterpret_cast<u16*>(&h);
}

// fast GELU: tanh form computed as u * sigmoid(2y). Validated r1-r4:
// absmax unchanged (0.03125), bf16 rounding dominates.
__device__ __forceinline__ float gelu_fast(float u){
  float uu = u * u;
  float e = __expf(u * fmaf(uu, -0.0713548163f, -1.5957691216f));
  return u * __builtin_amdgcn_rcpf(1.f + e);
}

// XOR bank swizzle for [R][192] u16 tiles read as one-row-per-lane b128
// fragments. Stride 192 u16 = 96 dwords = 0 mod 32 -> UNswizzled would be
// 16-way conflict; with XOR of (row&7) 16B-granules, rows 0..7 cover all
// 32 banks -> 2-way (free). Applied at BOTH write and read (rule #21).
__device__ __forceinline__ int swz(int row, int col){
  return row * 192 + (col ^ ((row & 7) << 3));
}

// ---------------- weight transpose+convert: W f32 (KxN) -> Wt bf16 (NxK) ----
__global__ void transpose_all(const float* __restrict__ w0, u16* __restrict__ d0,   // 192x576
                              const float* __restrict__ w1, u16* __restrict__ d1,   // 192x192
                              const float* __restrict__ w2, u16* __restrict__ d2,   // 192x768
                              const float* __restrict__ w3, u16* __restrict__ d3)   // 768x192
{
  int seg = blockIdx.y;
  const float* s; u16* d; int K, N;
  if      (seg == 0){ s = w0; d = d0; K = 192; N = 576; }
  else if (seg == 1){ s = w1; d = d1; K = 192; N = 192; }
  else if (seg == 2){ s = w2; d = d2; K = 192; N = 768; }
  else              { s = w3; d = d3; K = 768; N = 192; }
  int idx = blockIdx.x * 256 + threadIdx.x;
  if (idx < K * N){
    int k = idx / N, n = idx % N;
    d[n * K + k] = f2bf(s[idx]);
  }
}

// ---------------- K1: fused LN1 + QKV + window attention + proj + residual
// One block per 8x8 window (4096 blocks, 256 threads = 4 waves).
// v5 = r0 staging structure (direct global->LDS, short-lived regs; the r4
// reg-prefetch port spilled: VGPR 80->128, WRITE_SIZE 196->850MB)
//    + swz swizzle on hw/wch (16-way -> 2-way; validated r4: 5.8e7 -> 6.7e6).
__global__ __launch_bounds__(256, 2) void win_attn(
    const float* __restrict__ x,  const float* __restrict__ g1, const float* __restrict__ b1,
    const u16* __restrict__ wqkvT, const float* __restrict__ bqkv,
    const u16* __restrict__ wprojT, const float* __restrict__ bproj,
    float* __restrict__ out)
{
  __shared__ u16 hw[64 * 192];    // LN1'd window tokens, bf16, SWIZZLED
  __shared__ u16 wch[96 * 192];   // per-head qkv weight chunk, SWIZZLED; aliased:
  u16* Ql = wch;                  // 64 x 40
  u16* Kl = wch + 64 * 40;        // 64 x 40
  u16* Vt = Kl  + 64 * 40;        // 32 x 72 (V transposed: [ch][token])
  u16* Pl = Vt  + 32 * 72;        // 64 x 72 (P, rows wave-private)

  const int tid = threadIdx.x, lane = tid & 63, w = tid >> 6;
  const int l15 = lane & 15, quad = lane >> 4;
  const int wid = blockIdx.x;
  const int b = wid >> 10, hy = (wid >> 5) & 31, wx = wid & 31;

  // ---- LN1 into hw: 4 lanes per token, 16 tokens per wave ----
  {
    int n = w * 16 + (lane >> 2), p = lane & 3;
    int hr = hy * 8 + (n >> 3), wcc = wx * 8 + (n & 7);
    size_t tg = ((size_t)(b * 256 + hr)) * 256 + wcc;
    const float* xr = x + tg * 192 + p * 48;
    float v[48];
    #pragma unroll
    for (int c = 0; c < 12; c++) *(float4*)(v + c * 4) = *(const float4*)(xr + c * 4);
    float s = 0.f, ss = 0.f;
    #pragma unroll
    for (int i = 0; i < 48; i++){ s += v[i]; ss += v[i] * v[i]; }
    s += __shfl_xor(s, 1); ss += __shfl_xor(ss, 1);
    s += __shfl_xor(s, 2); ss += __shfl_xor(ss, 2);
    float m  = s * (1.f / 192.f);
    float rs = rsqrtf(ss * (1.f / 192.f) - m * m + 1e-5f);
    #pragma unroll
    for (int c = 0; c < 12; c++){
      float4 gv = *(const float4*)(g1 + p * 48 + c * 4);
      float4 bv = *(const float4*)(b1 + p * 48 + c * 4);
      short4v t;
      t.x = (short)f2bf((v[c*4+0] - m) * rs * gv.x + bv.x);
      t.y = (short)f2bf((v[c*4+1] - m) * rs * gv.y + bv.y);
      t.z = (short)f2bf((v[c*4+2] - m) * rs * gv.z + bv.z);
      t.w = (short)f2bf((v[c*4+3] - m) * rs * gv.w + bv.w);
      *(short4v*)&hw[swz(n, p * 48 + c * 4)] = t;   // 8B chunk stays in 16B granule
    }
  }

  const int qrow = w * 16 + quad * 4;   // +r gives this lane's C-layout rows
  f32x4 oall[6][2];
  #pragma unroll
  for (int h = 0; h < 6; h++)
    #pragma unroll
    for (int nt = 0; nt < 2; nt++) oall[h][nt] = (f32x4){0.f, 0.f, 0.f, 0.f};

  #pragma unroll
  for (int head = 0; head < 6; ++head){
    __syncthreads();   // protect wch region (Kl/Vt/Pl) from previous head's readers
    // stage this head's 96x192 slice of wqkvT (rows: q,k,v blocks), bf16
    #pragma unroll
    for (int it = 0; it < 9; ++it){
      int c = tid + it * 256;
      int row = c / 24, cc = c % 24;
      int gr = (row >> 5) * 192 + head * 32 + (row & 31);
      *(uint4*)&wch[swz(row, cc * 8)] = *(const uint4*)(wqkvT + (size_t)gr * 192 + cc * 8);
    }
    __syncthreads();
    // QKV: wave's 16 token rows x 32 cols per matrix, K=192
    f32x4 acc[3][2];
    #pragma unroll
    for (int mat = 0; mat < 3; mat++)
      #pragma unroll
      for (int nt = 0; nt < 2; nt++) acc[mat][nt] = (f32x4){0.f, 0.f, 0.f, 0.f};
    #pragma unroll
    for (int k = 0; k < 6; k++){
      short8 af = *(const short8*)&hw[swz(w * 16 + l15, k * 32 + quad * 8)];
      #pragma unroll
      for (int mat = 0; mat < 3; mat++)
        #pragma unroll
        for (int nt = 0; nt < 2; nt++){
          short8 bfv = *(const short8*)&wch[swz(mat * 32 + nt * 16 + l15, k * 32 + quad * 8)];
          acc[mat][nt] = __builtin_amdgcn_mfma_f32_16x16x32_bf16(af, bfv, acc[mat][nt], 0, 0, 0);
        }
    }
    __syncthreads();   // all waves done reading wch before aliased writes
    #pragma unroll
    for (int nt = 0; nt < 2; nt++){
      float bq = bqkv[      head * 32 + nt * 16 + l15];
      float bk = bqkv[192 + head * 32 + nt * 16 + l15];
      float bv = bqkv[384 + head * 32 + nt * 16 + l15];
      #pragma unroll
      for (int r = 0; r < 4; r++){
        Ql[(qrow + r) * 40 + nt * 16 + l15] = f2bf(acc[0][nt][r] + bq);
        Kl[(qrow + r) * 40 + nt * 16 + l15] = f2bf(acc[1][nt][r] + bk);
        Vt[(nt * 16 + l15) * 72 + qrow + r] = f2bf(acc[2][nt][r] + bv);
      }
    }
    __syncthreads();   // Kl/Vt are cross-wave
    // S = Q K^T : hd=32 == one 16x16x32 MFMA k-step
    short8 aq = *(const short8*)&Ql[(w * 16 + l15) * 40 + quad * 8];
    f32x4 sa[4];
    #pragma unroll
    for (int kt = 0; kt < 4; kt++){
      short8 bk8 = *(const short8*)&Kl[(kt * 16 + l15) * 40 + quad * 8];
      sa[kt] = __builtin_amdgcn_mfma_f32_16x16x32_bf16(aq, bk8, (f32x4){0.f,0.f,0.f,0.f}, 0, 0, 0);
    }
    const float scale = 0.17677669529663687f;  // 32^-0.5
    float inv[4];
    #pragma unroll
    for (int r = 0; r < 4; r++){
      float s0 = sa[0][r] * scale, s1 = sa[1][r] * scale;
      float s2 = sa[2][r] * scale, s3 = sa[3][r] * scale;
      float mx = fmaxf(fmaxf(s0, s1), fmaxf(s2, s3));
      mx = fmaxf(mx, __shfl_xor(mx, 1)); mx = fmaxf(mx, __shfl_xor(mx, 2));
      mx = fmaxf(mx, __shfl_xor(mx, 4)); mx = fmaxf(mx, __shfl_xor(mx, 8));
      float p0 = __expf(s0 - mx), p1 = __expf(s1 - mx);
      float p2 = __expf(s2 - mx), p3 = __expf(s3 - mx);
      float l = p0 + p1 + p2 + p3;
      l += __shfl_xor(l, 1); l += __shfl_xor(l, 2);
      l += __shfl_xor(l, 4); l += __shfl_xor(l, 8);
      inv[r] = 1.f / l;
      Pl[(qrow + r) * 72 +      l15] = f2bf(p0);
      Pl[(qrow + r) * 72 + 16 + l15] = f2bf(p1);
      Pl[(qrow + r) * 72 + 32 + l15] = f2bf(p2);
      Pl[(qrow + r) * 72 + 48 + l15] = f2bf(p3);
    }
    // O = P V  (Pl rows wave-private; Vt barrier already passed)
    f32x4 oa[2];
    oa[0] = (f32x4){0.f,0.f,0.f,0.f}; oa[1] = (f32x4){0.f,0.f,0.f,0.f};
    #pragma unroll
    for (int ks = 0; ks < 2; ks++){
      short8 ap = *(const short8*)&Pl[(w * 16 + l15) * 72 + ks * 32 + quad * 8];
      #pragma unroll
      for (int nt = 0; nt < 2; nt++){
        short8 bv8 = *(const short8*)&Vt[(nt * 16 + l15) * 72 + ks * 32 + quad * 8];
        oa[nt] = __builtin_amdgcn_mfma_f32_16x16x32_bf16(ap, bv8, oa[nt], 0, 0, 0);
      }
    }
    #pragma unroll
    for (int nt = 0; nt < 2; nt++)
      #pragma unroll
      for (int r = 0; r < 4; r++)
        oall[head][nt][r] = oa[nt][r] * inv[r];
  }

  // stash O (64x192, bf16) into hw (rows wave-private; hw's LN content is dead)
  #pragma unroll
  for (int h = 0; h < 6; h++)
    #pragma unroll
    for (int nt = 0; nt < 2; nt++)
      #pragma unroll
      for (int r = 0; r < 4; r++)
        hw[swz(qrow + r, h * 32 + nt * 16 + l15)] = f2bf(oall[h][nt][r]);

  // proj: xo = x + O @ w_proj + b_proj  (B-frags streamed from L2-resident wprojT;
  // OK here: runs once, no barrier loop, latency amortized over 72 loads)
  f32x4 accP[12];
  #pragma unroll
  for (int nt = 0; nt < 12; nt++) accP[nt] = (f32x4){0.f,0.f,0.f,0.f};
  #pragma unroll
  for (int k = 0; k < 6; k++){
    short8 af = *(const short8*)&hw[swz(w * 16 + l15, k * 32 + quad * 8)];
    #pragma unroll
    for (int nt = 0; nt < 12; nt++){
      short8 bfv = *(const short8*)(wprojT + (size_t)(nt * 16 + l15) * 192 + k * 32 + quad * 8);
      accP[nt] = __builtin_amdgcn_mfma_f32_16x16x32_bf16(af, bfv, accP[nt], 0, 0, 0);
    }
  }
  #pragma unroll
  for (int r = 0; r < 4; r++){
    int nn = qrow + r;
    int hr = hy * 8 + (nn >> 3), wcc = wx * 8 + (nn & 7);
    size_t tg = ((size_t)(b * 256 + hr)) * 256 + wcc;
    #pragma unroll
    for (int nt = 0; nt < 12; nt++){
      int col = nt * 16 + l15;
      size_t idx = tg * 192 + col;
      out[idx] = accP[nt][r] + bproj[col] + x[idx];
    }
  }
}

// ---------------- K2: fused LN2 + fc1 + GELU + fc2 + residual (in-place on io)
// v4 kept: T14 prefetch pipeline (6 uint4, no spill: VGPR 100) + swizzled
// h2t/w1b, wave-private Ut, 2 barriers/chunk.
__global__ __launch_bounds__(256, 2) void mlp_fused(
    const float* __restrict__ g2, const float* __restrict__ b2,
    const u16* __restrict__ wfc1T, const float* __restrict__ bfc1,
    const u16* __restrict__ wfc2T, const float* __restrict__ bfc2,
    float* __restrict__ io)
{
  __shared__ u16 h2t[64 * 192];   // 24.6 KB LN2'd tokens, SWIZZLED (rows wave-private)
  __shared__ u16 w1b[32 * 192];   // 12.3 KB fc1 chunk [fc1col][k], SWIZZLED
  __shared__ u16 w2b[192 * 40];   // 15.4 KB fc2 chunk [outcol][kl] (2-way ok)
  __shared__ u16 Ut [64 * 40];    //  5.1 KB gelu(U) [tok][kl-local] (wave-private rows)

  const int tid = threadIdx.x, lane = tid & 63, w = tid >> 6;
  const int l15 = lane & 15, quad = lane >> 4;
  const int t0 = blockIdx.x * 64;

  // staging maps (per thread, 3 uint4 each):
  const int c0 = tid, c1 = tid + 256, c2 = tid + 512;
  const int w1r0 = c0 / 24, w1c0 = c0 % 24;
  const int w1r1 = c1 / 24, w1c1 = c1 % 24;
  const int w1r2 = c2 / 24, w1c2 = c2 % 24;
  const int w2r0 = c0 >> 2, w2c0 = c0 & 3;
  const int w2r1 = c1 >> 2, w2c1 = c1 & 3;
  const int w2r2 = c2 >> 2, w2c2 = c2 & 3;

  // ---- prefetch chunk 0 weights into regs (latency hides under LN) ----
  uint4 r1a, r1b, r1c, r2a, r2b, r2c;
  r1a = *(const uint4*)(wfc1T + (size_t)w1r0 * 192 + w1c0 * 8);
  r1b = *(const uint4*)(wfc1T + (size_t)w1r1 * 192 + w1c1 * 8);
  r1c = *(const uint4*)(wfc1T + (size_t)w1r2 * 192 + w1c2 * 8);
  r2a = *(const uint4*)(wfc2T + (size_t)w2r0 * 768 + w2c0 * 8);
  r2b = *(const uint4*)(wfc2T + (size_t)w2r1 * 768 + w2c1 * 8);
  r2c = *(const uint4*)(wfc2T + (size_t)w2r2 * 768 + w2c2 * 8);

  // ---- LN2 into h2t ----
  {
    int n = w * 16 + (lane >> 2), p = lane & 3;
    const float* xr = io + (size_t)(t0 + n) * 192 + p * 48;
    float v[48];
    #pragma unroll
    for (int c = 0; c < 12; c++) *(float4*)(v + c * 4) = *(const float4*)(xr + c * 4);
    float s = 0.f, ss = 0.f;
    #pragma unroll
    for (int i = 0; i < 48; i++){ s += v[i]; ss += v[i] * v[i]; }
    s += __shfl_xor(s, 1); ss += __shfl_xor(ss, 1);
    s += __shfl_xor(s, 2); ss += __shfl_xor(ss, 2);
    float m  = s * (1.f / 192.f);
    float rs = rsqrtf(ss * (1.f / 192.f) - m * m + 1e-5f);
    #pragma unroll
    for (int c = 0; c < 12; c++){
      float4 gv = *(const float4*)(g2 + p * 48 + c * 4);
      float4 bv = *(const float4*)(b2 + p * 48 + c * 4);
      short4v t;
      t.x = (short)f2bf((v[c*4+0] - m) * rs * gv.x + bv.x);
      t.y = (short)f2bf((v[c*4+1] - m) * rs * gv.y + bv.y);
      t.z = (short)f2bf((v[c*4+2] - m) * rs * gv.z + bv.z);
      t.w = (short)f2bf((v[c*4+3] - m) * rs * gv.w + bv.w);
      *(short4v*)&h2t[swz(n, p * 48 + c * 4)] = t;
    }
  }

  f32x4 accO[12];
  #pragma unroll
  for (int nt = 0; nt < 12; nt++) accO[nt] = (f32x4){0.f,0.f,0.f,0.f};

  for (int ch = 0; ch < 24; ++ch){
    // commit staged regs to LDS (data arrived during prev chunk's compute)
    *(uint4*)&w1b[swz(w1r0, w1c0 * 8)] = r1a;
    *(uint4*)&w1b[swz(w1r1, w1c1 * 8)] = r1b;
    *(uint4*)&w1b[swz(w1r2, w1c2 * 8)] = r1c;
    *(uint4*)&w2b[w2r0 * 40 + w2c0 * 8] = r2a;
    *(uint4*)&w2b[w2r1 * 40 + w2c1 * 8] = r2b;
    *(uint4*)&w2b[w2r2 * 40 + w2c2 * 8] = r2c;
    // issue next chunk's loads (no wait; lands during this chunk's compute)
    if (ch < 23){
      int chn = ch + 1;
      r1a = *(const uint4*)(wfc1T + (size_t)(chn * 32 + w1r0) * 192 + w1c0 * 8);
      r1b = *(const uint4*)(wfc1T + (size_t)(chn * 32 + w1r1) * 192 + w1c1 * 8);
      r1c = *(const uint4*)(wfc1T + (size_t)(chn * 32 + w1r2) * 192 + w1c2 * 8);
      r2a = *(const uint4*)(wfc2T + (size_t)w2r0 * 768 + chn * 32 + w2c0 * 8);
      r2b = *(const uint4*)(wfc2T + (size_t)w2r1 * 768 + chn * 32 + w2c1 * 8);
      r2c = *(const uint4*)(wfc2T + (size_t)w2r2 * 768 + chn * 32 + w2c2 * 8);
    }
    __syncthreads();   // staged w1b/w2b visible (also h2t on first iter)

    // U = h2 @ w1^T : wave's 16 tokens x 32 fc1-cols, K=192
    f32x4 au[2];
    au[0] = (f32x4){0.f,0.f,0.f,0.f}; au[1] = (f32x4){0.f,0.f,0.f,0.f};
    #pragma unroll
    for (int k = 0; k < 6; k++){
      short8 af = *(const short8*)&h2t[swz(w * 16 + l15, k * 32 + quad * 8)];
      #pragma unroll
      for (int nt = 0; nt < 2; nt++){
        short8 bfv = *(const short8*)&w1b[swz(nt * 16 + l15, k * 32 + quad * 8)];
        au[nt] = __builtin_amdgcn_mfma_f32_16x16x32_bf16(af, bfv, au[nt], 0, 0, 0);
      }
    }
    // bias + fast GELU -> Ut (wave-private rows; same-wave write->read, no barrier)
    #pragma unroll
    for (int nt = 0; nt < 2; nt++){
      float bb = bfc1[ch * 32 + nt * 16 + l15];
      #pragma unroll
      for (int r = 0; r < 4; r++){
        float u = au[nt][r] + bb;
        Ut[(w * 16 + quad * 4 + r) * 40 + nt * 16 + l15] = f2bf(gelu_fast(u));
      }
    }
    // fc2 partial: A = Ut wave rows [16 x 32] (one b128/lane), B = w2b, K=32
    short8 auf = *(const short8*)&Ut[(w * 16 + l15) * 40 + quad * 8];
    #pragma unroll
    for (int nt = 0; nt < 12; nt++){
      short8 bfv = *(const short8*)&w2b[(nt * 16 + l15) * 40 + quad * 8];
      accO[nt] = __builtin_amdgcn_mfma_f32_16x16x32_bf16(auf, bfv, accO[nt], 0, 0, 0);
    }
    __syncthreads();   // all reads of w1b/w2b done before next chunk's ds_writes
  }

  // epilogue: out = xo + (accO + b_fc2), in place (wave-disjoint rows)
  #pragma unroll
  for (int nt = 0; nt < 12; nt++){
    int col = nt * 16 + l15;
    float bb = bfc2[col];
    #pragma unroll
    for (int r = 0; r < 4; r++){
      int row = t0 + w * 16 + quad * 4 + r;
      size_t idx = (size_t)row * 192 + col;
      io[idx] = accO[nt][r] + bb + io[idx];
    }
  }
}

// ------------------------------------------------------------------------
extern "C" void kernel_launch(void* const* d_in, const int* in_sizes, int n_in,
                              void* d_out, int out_size, void* d_ws, size_t ws_size,
                              hipStream_t stream) {
  const float* x      = (const float*)d_in[0];
  const float* g1     = (const float*)d_in[1];
  const float* b1     = (const float*)d_in[2];
  const float* w_qkv  = (const float*)d_in[3];
  const float* b_qkv  = (const float*)d_in[4];
  const float* w_proj = (const float*)d_in[5];
  const float* b_proj = (const float*)d_in[6];
  const float* g2     = (const float*)d_in[7];
  const float* b2     = (const float*)d_in[8];
  const float* w_fc1  = (const float*)d_in[9];
  const float* b_fc1  = (const float*)d_in[10];
  const float* w_fc2  = (const float*)d_in[11];
  const float* b_fc2  = (const float*)d_in[12];
  float* out = (float*)d_out;

  // workspace: transposed bf16 weights only (<1 MB)
  u16* wqkvT  = (u16*)d_ws;                      // 576x192
  u16* wprojT = wqkvT  + 576 * 192;              // 192x192
  u16* wfc1T  = wprojT + 192 * 192;              // 768x192
  u16* wfc2T  = wfc1T  + 768 * 192;              // 192x768

  transpose_all<<<dim3(576, 4), 256, 0, stream>>>(w_qkv, wqkvT, w_proj, wprojT,
                                                  w_fc1, wfc1T, w_fc2, wfc2T);
  // d_out = x + attn(LN1(x)) @ w_proj + b_proj   (window-fused)
  win_attn<<<4096, 256, 0, stream>>>(x, g1, b1, wqkvT, b_qkv, wprojT, b_proj, out);
  // d_out += gelu(LN2(d_out) @ w_fc1 + b_fc1) @ w_fc2 + b_fc2   (in place)
  mlp_fused<<<4096, 256, 0, stream>>>(g2, b2, wfc1T, b_fc1, wfc2T, b_fc2, out);
}

// Round 6
// 943.649 us; speedup vs baseline: 1.2420x; 1.2420x over previous
//
#include <hip/hip_runtime.h>
#include <hip/hip_bf16.h>

typedef unsigned short u16;
typedef __attribute__((ext_vector_type(8))) short short8;
typedef __attribute__((ext_vector_type(4))) short short4v;
typedef __attribute__((ext_vector_type(4))) float f32x4;

__device__ __forceinline__ u16 f2bf(float f){
  __hip_bfloat16 h = __float2bfloat16(f);
  return *reinterpret_cast<u16*>(&h);
}

// fast GELU: tanh form computed as u * sigmoid(2y). Validated r1-r5:
// absmax unchanged (0.03125), bf16 rounding dominates.
__device__ __forceinline__ float gelu_fast(float u){
  float uu = u * u;
  float e = __expf(u * fmaf(uu, -0.0713548163f, -1.5957691216f));
  return u * __builtin_amdgcn_rcpf(1.f + e);
}

// XOR bank swizzle for [R][192] u16 tiles (kept ONLY in mlp_fused, where the
// r4/r5 totals estimate v4 ~= 403us vs v3's 412; in win_attn the same swizzle
// cost +200us (r5 A/B: 400->610) and is REMOVED — stride-200 padding already
// spreads rows across bank-quads (100 dwords == 4 mod 32)).
__device__ __forceinline__ int swz(int row, int col){
  return row * 192 + (col ^ ((row & 7) << 3));
}

// ---------------- weight transpose+convert: W f32 (KxN) -> Wt bf16 (NxK) ----
__global__ void transpose_all(const float* __restrict__ w0, u16* __restrict__ d0,   // 192x576
                              const float* __restrict__ w1, u16* __restrict__ d1,   // 192x192
                              const float* __restrict__ w2, u16* __restrict__ d2,   // 192x768
                              const float* __restrict__ w3, u16* __restrict__ d3)   // 768x192
{
  int seg = blockIdx.y;
  const float* s; u16* d; int K, N;
  if      (seg == 0){ s = w0; d = d0; K = 192; N = 576; }
  else if (seg == 1){ s = w1; d = d1; K = 192; N = 192; }
  else if (seg == 2){ s = w2; d = d2; K = 192; N = 768; }
  else              { s = w3; d = d3; K = 768; N = 192; }
  int idx = blockIdx.x * 256 + threadIdx.x;
  if (idx < K * N){
    int k = idx / N, n = idx % N;
    d[n * K + k] = f2bf(s[idx]);
  }
}

// ---------------- K1: fused LN1 + QKV + window attention + proj + residual
// One block per 8x8 window (4096 blocks, 256 threads = 4 waves).
// r0-EXACT revert: stride-200 LDS (inherent bank spread), direct global->LDS
// staging, no prefetch (r4 spilled), no swizzle (r5: +200us regression).
__global__ __launch_bounds__(256, 2) void win_attn(
    const float* __restrict__ x,  const float* __restrict__ g1, const float* __restrict__ b1,
    const u16* __restrict__ wqkvT, const float* __restrict__ bqkv,
    const u16* __restrict__ wprojT, const float* __restrict__ bproj,
    float* __restrict__ out)
{
  __shared__ u16 hw[64 * 200];    // LN1'd window tokens, bf16 (rows wave-private)
  __shared__ u16 wch[96 * 200];   // per-head qkv weight chunk; later aliased:
  u16* Ql = wch;                  // 64 x 40
  u16* Kl = wch + 64 * 40;        // 64 x 40
  u16* Vt = Kl  + 64 * 40;        // 32 x 72 (V transposed: [ch][token])
  u16* Pl = Vt  + 32 * 72;        // 64 x 72 (P, rows wave-private)

  const int tid = threadIdx.x, lane = tid & 63, w = tid >> 6;
  const int l15 = lane & 15, quad = lane >> 4;
  const int wid = blockIdx.x;
  const int b = wid >> 10, hy = (wid >> 5) & 31, wx = wid & 31;

  // ---- LN1 into hw: 4 lanes per token, 16 tokens per wave ----
  {
    int n = w * 16 + (lane >> 2), p = lane & 3;
    int hr = hy * 8 + (n >> 3), wcc = wx * 8 + (n & 7);
    size_t tg = ((size_t)(b * 256 + hr)) * 256 + wcc;
    const float* xr = x + tg * 192 + p * 48;
    float v[48];
    #pragma unroll
    for (int c = 0; c < 12; c++) *(float4*)(v + c * 4) = *(const float4*)(xr + c * 4);
    float s = 0.f, ss = 0.f;
    #pragma unroll
    for (int i = 0; i < 48; i++){ s += v[i]; ss += v[i] * v[i]; }
    s += __shfl_xor(s, 1); ss += __shfl_xor(ss, 1);
    s += __shfl_xor(s, 2); ss += __shfl_xor(ss, 2);
    float m  = s * (1.f / 192.f);
    float rs = rsqrtf(ss * (1.f / 192.f) - m * m + 1e-5f);
    #pragma unroll
    for (int c = 0; c < 12; c++){
      float4 gv = *(const float4*)(g1 + p * 48 + c * 4);
      float4 bv = *(const float4*)(b1 + p * 48 + c * 4);
      short4v t;
      t.x = (short)f2bf((v[c*4+0] - m) * rs * gv.x + bv.x);
      t.y = (short)f2bf((v[c*4+1] - m) * rs * gv.y + bv.y);
      t.z = (short)f2bf((v[c*4+2] - m) * rs * gv.z + bv.z);
      t.w = (short)f2bf((v[c*4+3] - m) * rs * gv.w + bv.w);
      *(short4v*)&hw[n * 200 + p * 48 + c * 4] = t;
    }
  }

  const int qrow = w * 16 + quad * 4;   // +r gives this lane's C-layout rows
  f32x4 oall[6][2];
  #pragma unroll
  for (int h = 0; h < 6; h++)
    #pragma unroll
    for (int nt = 0; nt < 2; nt++) oall[h][nt] = (f32x4){0.f, 0.f, 0.f, 0.f};

  #pragma unroll
  for (int head = 0; head < 6; ++head){
    __syncthreads();   // protect wch region (Kl/Vt/Pl) from previous head's readers
    // stage this head's 96x192 slice of wqkvT (rows: q,k,v blocks), bf16
    #pragma unroll
    for (int it = 0; it < 9; ++it){
      int c = tid + it * 256;
      int row = c / 24, cc = c % 24;
      int gr = (row >> 5) * 192 + head * 32 + (row & 31);
      *(uint4*)&wch[row * 200 + cc * 8] = *(const uint4*)(wqkvT + (size_t)gr * 192 + cc * 8);
    }
    __syncthreads();
    // QKV: wave's 16 token rows x 32 cols per matrix, K=192
    f32x4 acc[3][2];
    #pragma unroll
    for (int mat = 0; mat < 3; mat++)
      #pragma unroll
      for (int nt = 0; nt < 2; nt++) acc[mat][nt] = (f32x4){0.f, 0.f, 0.f, 0.f};
    #pragma unroll
    for (int k = 0; k < 6; k++){
      short8 af = *(const short8*)&hw[(w * 16 + l15) * 200 + k * 32 + quad * 8];
      #pragma unroll
      for (int mat = 0; mat < 3; mat++)
        #pragma unroll
        for (int nt = 0; nt < 2; nt++){
          short8 bfv = *(const short8*)&wch[(mat * 32 + nt * 16 + l15) * 200 + k * 32 + quad * 8];
          acc[mat][nt] = __builtin_amdgcn_mfma_f32_16x16x32_bf16(af, bfv, acc[mat][nt], 0, 0, 0);
        }
    }
    __syncthreads();   // all waves done reading wch before aliased writes
    #pragma unroll
    for (int nt = 0; nt < 2; nt++){
      float bq = bqkv[      head * 32 + nt * 16 + l15];
      float bk = bqkv[192 + head * 32 + nt * 16 + l15];
      float bv = bqkv[384 + head * 32 + nt * 16 + l15];
      #pragma unroll
      for (int r = 0; r < 4; r++){
        Ql[(qrow + r) * 40 + nt * 16 + l15] = f2bf(acc[0][nt][r] + bq);
        Kl[(qrow + r) * 40 + nt * 16 + l15] = f2bf(acc[1][nt][r] + bk);
        Vt[(nt * 16 + l15) * 72 + qrow + r] = f2bf(acc[2][nt][r] + bv);
      }
    }
    __syncthreads();   // Kl/Vt are cross-wave
    // S = Q K^T : hd=32 == one 16x16x32 MFMA k-step
    short8 aq = *(const short8*)&Ql[(w * 16 + l15) * 40 + quad * 8];
    f32x4 sa[4];
    #pragma unroll
    for (int kt = 0; kt < 4; kt++){
      short8 bk8 = *(const short8*)&Kl[(kt * 16 + l15) * 40 + quad * 8];
      sa[kt] = __builtin_amdgcn_mfma_f32_16x16x32_bf16(aq, bk8, (f32x4){0.f,0.f,0.f,0.f}, 0, 0, 0);
    }
    const float scale = 0.17677669529663687f;  // 32^-0.5
    float inv[4];
    #pragma unroll
    for (int r = 0; r < 4; r++){
      float s0 = sa[0][r] * scale, s1 = sa[1][r] * scale;
      float s2 = sa[2][r] * scale, s3 = sa[3][r] * scale;
      float mx = fmaxf(fmaxf(s0, s1), fmaxf(s2, s3));
      mx = fmaxf(mx, __shfl_xor(mx, 1)); mx = fmaxf(mx, __shfl_xor(mx, 2));
      mx = fmaxf(mx, __shfl_xor(mx, 4)); mx = fmaxf(mx, __shfl_xor(mx, 8));
      float p0 = __expf(s0 - mx), p1 = __expf(s1 - mx);
      float p2 = __expf(s2 - mx), p3 = __expf(s3 - mx);
      float l = p0 + p1 + p2 + p3;
      l += __shfl_xor(l, 1); l += __shfl_xor(l, 2);
      l += __shfl_xor(l, 4); l += __shfl_xor(l, 8);
      inv[r] = 1.f / l;
      Pl[(qrow + r) * 72 +      l15] = f2bf(p0);
      Pl[(qrow + r) * 72 + 16 + l15] = f2bf(p1);
      Pl[(qrow + r) * 72 + 32 + l15] = f2bf(p2);
      Pl[(qrow + r) * 72 + 48 + l15] = f2bf(p3);
    }
    // O = P V  (Pl rows wave-private; Vt barrier already passed)
    f32x4 oa[2];
    oa[0] = (f32x4){0.f,0.f,0.f,0.f}; oa[1] = (f32x4){0.f,0.f,0.f,0.f};
    #pragma unroll
    for (int ks = 0; ks < 2; ks++){
      short8 ap = *(const short8*)&Pl[(w * 16 + l15) * 72 + ks * 32 + quad * 8];
      #pragma unroll
      for (int nt = 0; nt < 2; nt++){
        short8 bv8 = *(const short8*)&Vt[(nt * 16 + l15) * 72 + ks * 32 + quad * 8];
        oa[nt] = __builtin_amdgcn_mfma_f32_16x16x32_bf16(ap, bv8, oa[nt], 0, 0, 0);
      }
    }
    #pragma unroll
    for (int nt = 0; nt < 2; nt++)
      #pragma unroll
      for (int r = 0; r < 4; r++)
        oall[head][nt][r] = oa[nt][r] * inv[r];
  }

  // stash O (64x192, bf16) into hw (rows wave-private; hw's LN content is dead)
  #pragma unroll
  for (int h = 0; h < 6; h++)
    #pragma unroll
    for (int nt = 0; nt < 2; nt++)
      #pragma unroll
      for (int r = 0; r < 4; r++)
        hw[(qrow + r) * 200 + h * 32 + nt * 16 + l15] = f2bf(oall[h][nt][r]);

  // proj: xo = x + O @ w_proj + b_proj  (B-frags streamed from L2-resident wprojT)
  f32x4 accP[12];
  #pragma unroll
  for (int nt = 0; nt < 12; nt++) accP[nt] = (f32x4){0.f,0.f,0.f,0.f};
  #pragma unroll
  for (int k = 0; k < 6; k++){
    short8 af = *(const short8*)&hw[(w * 16 + l15) * 200 + k * 32 + quad * 8];
    #pragma unroll
    for (int nt = 0; nt < 12; nt++){
      short8 bfv = *(const short8*)(wprojT + (size_t)(nt * 16 + l15) * 192 + k * 32 + quad * 8);
      accP[nt] = __builtin_amdgcn_mfma_f32_16x16x32_bf16(af, bfv, accP[nt], 0, 0, 0);
    }
  }
  #pragma unroll
  for (int r = 0; r < 4; r++){
    int nn = qrow + r;
    int hr = hy * 8 + (nn >> 3), wcc = wx * 8 + (nn & 7);
    size_t tg = ((size_t)(b * 256 + hr)) * 256 + wcc;
    #pragma unroll
    for (int nt = 0; nt < 12; nt++){
      int col = nt * 16 + l15;
      size_t idx = tg * 192 + col;
      out[idx] = accP[nt][r] + bproj[col] + x[idx];
    }
  }
}

// ---------------- K2: fused LN2 + fc1 + GELU + fc2 + residual (in-place on io)
// v4 kept byte-exact: T14 prefetch pipeline (6 uint4, no spill) + swizzled
// h2t/w1b, wave-private Ut, 2 barriers/chunk. Estimated ~403us (r4/r5 totals).
__global__ __launch_bounds__(256, 2) void mlp_fused(
    const float* __restrict__ g2, const float* __restrict__ b2,
    const u16* __restrict__ wfc1T, const float* __restrict__ bfc1,
    const u16* __restrict__ wfc2T, const float* __restrict__ bfc2,
    float* __restrict__ io)
{
  __shared__ u16 h2t[64 * 192];   // 24.6 KB LN2'd tokens, SWIZZLED (rows wave-private)
  __shared__ u16 w1b[32 * 192];   // 12.3 KB fc1 chunk [fc1col][k], SWIZZLED
  __shared__ u16 w2b[192 * 40];   // 15.4 KB fc2 chunk [outcol][kl] (2-way ok)
  __shared__ u16 Ut [64 * 40];    //  5.1 KB gelu(U) [tok][kl-local] (wave-private rows)

  const int tid = threadIdx.x, lane = tid & 63, w = tid >> 6;
  const int l15 = lane & 15, quad = lane >> 4;
  const int t0 = blockIdx.x * 64;

  // staging maps (per thread, 3 uint4 each):
  const int c0 = tid, c1 = tid + 256, c2 = tid + 512;
  const int w1r0 = c0 / 24, w1c0 = c0 % 24;
  const int w1r1 = c1 / 24, w1c1 = c1 % 24;
  const int w1r2 = c2 / 24, w1c2 = c2 % 24;
  const int w2r0 = c0 >> 2, w2c0 = c0 & 3;
  const int w2r1 = c1 >> 2, w2c1 = c1 & 3;
  const int w2r2 = c2 >> 2, w2c2 = c2 & 3;

  // ---- prefetch chunk 0 weights into regs (latency hides under LN) ----
  uint4 r1a, r1b, r1c, r2a, r2b, r2c;
  r1a = *(const uint4*)(wfc1T + (size_t)w1r0 * 192 + w1c0 * 8);
  r1b = *(const uint4*)(wfc1T + (size_t)w1r1 * 192 + w1c1 * 8);
  r1c = *(const uint4*)(wfc1T + (size_t)w1r2 * 192 + w1c2 * 8);
  r2a = *(const uint4*)(wfc2T + (size_t)w2r0 * 768 + w2c0 * 8);
  r2b = *(const uint4*)(wfc2T + (size_t)w2r1 * 768 + w2c1 * 8);
  r2c = *(const uint4*)(wfc2T + (size_t)w2r2 * 768 + w2c2 * 8);

  // ---- LN2 into h2t ----
  {
    int n = w * 16 + (lane >> 2), p = lane & 3;
    const float* xr = io + (size_t)(t0 + n) * 192 + p * 48;
    float v[48];
    #pragma unroll
    for (int c = 0; c < 12; c++) *(float4*)(v + c * 4) = *(const float4*)(xr + c * 4);
    float s = 0.f, ss = 0.f;
    #pragma unroll
    for (int i = 0; i < 48; i++){ s += v[i]; ss += v[i] * v[i]; }
    s += __shfl_xor(s, 1); ss += __shfl_xor(ss, 1);
    s += __shfl_xor(s, 2); ss += __shfl_xor(ss, 2);
    float m  = s * (1.f / 192.f);
    float rs = rsqrtf(ss * (1.f / 192.f) - m * m + 1e-5f);
    #pragma unroll
    for (int c = 0; c < 12; c++){
      float4 gv = *(const float4*)(g2 + p * 48 + c * 4);
      float4 bv = *(const float4*)(b2 + p * 48 + c * 4);
      short4v t;
      t.x = (short)f2bf((v[c*4+0] - m) * rs * gv.x + bv.x);
      t.y = (short)f2bf((v[c*4+1] - m) * rs * gv.y + bv.y);
      t.z = (short)f2bf((v[c*4+2] - m) * rs * gv.z + bv.z);
      t.w = (short)f2bf((v[c*4+3] - m) * rs * gv.w + bv.w);
      *(short4v*)&h2t[swz(n, p * 48 + c * 4)] = t;
    }
  }

  f32x4 accO[12];
  #pragma unroll
  for (int nt = 0; nt < 12; nt++) accO[nt] = (f32x4){0.f,0.f,0.f,0.f};

  for (int ch = 0; ch < 24; ++ch){
    // commit staged regs to LDS (data arrived during prev chunk's compute)
    *(uint4*)&w1b[swz(w1r0, w1c0 * 8)] = r1a;
    *(uint4*)&w1b[swz(w1r1, w1c1 * 8)] = r1b;
    *(uint4*)&w1b[swz(w1r2, w1c2 * 8)] = r1c;
    *(uint4*)&w2b[w2r0 * 40 + w2c0 * 8] = r2a;
    *(uint4*)&w2b[w2r1 * 40 + w2c1 * 8] = r2b;
    *(uint4*)&w2b[w2r2 * 40 + w2c2 * 8] = r2c;
    // issue next chunk's loads (no wait; lands during this chunk's compute)
    if (ch < 23){
      int chn = ch + 1;
      r1a = *(const uint4*)(wfc1T + (size_t)(chn * 32 + w1r0) * 192 + w1c0 * 8);
      r1b = *(const uint4*)(wfc1T + (size_t)(chn * 32 + w1r1) * 192 + w1c1 * 8);
      r1c = *(const uint4*)(wfc1T + (size_t)(chn * 32 + w1r2) * 192 + w1c2 * 8);
      r2a = *(const uint4*)(wfc2T + (size_t)w2r0 * 768 + chn * 32 + w2c0 * 8);
      r2b = *(const uint4*)(wfc2T + (size_t)w2r1 * 768 + chn * 32 + w2c1 * 8);
      r2c = *(const uint4*)(wfc2T + (size_t)w2r2 * 768 + chn * 32 + w2c2 * 8);
    }
    __syncthreads();   // staged w1b/w2b visible (also h2t on first iter)

    // U = h2 @ w1^T : wave's 16 tokens x 32 fc1-cols, K=192
    f32x4 au[2];
    au[0] = (f32x4){0.f,0.f,0.f,0.f}; au[1] = (f32x4){0.f,0.f,0.f,0.f};
    #pragma unroll
    for (int k = 0; k < 6; k++){
      short8 af = *(const short8*)&h2t[swz(w * 16 + l15, k * 32 + quad * 8)];
      #pragma unroll
      for (int nt = 0; nt < 2; nt++){
        short8 bfv = *(const short8*)&w1b[swz(nt * 16 + l15, k * 32 + quad * 8)];
        au[nt] = __builtin_amdgcn_mfma_f32_16x16x32_bf16(af, bfv, au[nt], 0, 0, 0);
      }
    }
    // bias + fast GELU -> Ut (wave-private rows; same-wave write->read, no barrier)
    #pragma unroll
    for (int nt = 0; nt < 2; nt++){
      float bb = bfc1[ch * 32 + nt * 16 + l15];
      #pragma unroll
      for (int r = 0; r < 4; r++){
        float u = au[nt][r] + bb;
        Ut[(w * 16 + quad * 4 + r) * 40 + nt * 16 + l15] = f2bf(gelu_fast(u));
      }
    }
    // fc2 partial: A = Ut wave rows [16 x 32] (one b128/lane), B = w2b, K=32
    short8 auf = *(const short8*)&Ut[(w * 16 + l15) * 40 + quad * 8];
    #pragma unroll
    for (int nt = 0; nt < 12; nt++){
      short8 bfv = *(const short8*)&w2b[(nt * 16 + l15) * 40 + quad * 8];
      accO[nt] = __builtin_amdgcn_mfma_f32_16x16x32_bf16(auf, bfv, accO[nt], 0, 0, 0);
    }
    __syncthreads();   // all reads of w1b/w2b done before next chunk's ds_writes
  }

  // epilogue: out = xo + (accO + b_fc2), in place (wave-disjoint rows)
  #pragma unroll
  for (int nt = 0; nt < 12; nt++){
    int col = nt * 16 + l15;
    float bb = bfc2[col];
    #pragma unroll
    for (int r = 0; r < 4; r++){
      int row = t0 + w * 16 + quad * 4 + r;
      size_t idx = (size_t)row * 192 + col;
      io[idx] = accO[nt][r] + bb + io[idx];
    }
  }
}

// ------------------------------------------------------------------------
extern "C" void kernel_launch(void* const* d_in, const int* in_sizes, int n_in,
                              void* d_out, int out_size, void* d_ws, size_t ws_size,
                              hipStream_t stream) {
  const float* x      = (const float*)d_in[0];
  const float* g1     = (const float*)d_in[1];
  const float* b1     = (const float*)d_in[2];
  const float* w_qkv  = (const float*)d_in[3];
  const float* b_qkv  = (const float*)d_in[4];
  const float* w_proj = (const float*)d_in[5];
  const float* b_proj = (const float*)d_in[6];
  const float* g2     = (const float*)d_in[7];
  const float* b2     = (const float*)d_in[8];
  const float* w_fc1  = (const float*)d_in[9];
  const float* b_fc1  = (const float*)d_in[10];
  const float* w_fc2  = (const float*)d_in[11];
  const float* b_fc2  = (const float*)d_in[12];
  float* out = (float*)d_out;

  // workspace: transposed bf16 weights only (<1 MB)
  u16* wqkvT  = (u16*)d_ws;                      // 576x192
  u16* wprojT = wqkvT  + 576 * 192;              // 192x192
  u16* wfc1T  = wprojT + 192 * 192;              // 768x192
  u16* wfc2T  = wfc1T  + 768 * 192;              // 192x768

  transpose_all<<<dim3(576, 4), 256, 0, stream>>>(w_qkv, wqkvT, w_proj, wprojT,
                                                  w_fc1, wfc1T, w_fc2, wfc2T);
  // d_out = x + attn(LN1(x)) @ w_proj + b_proj   (window-fused)
  win_attn<<<4096, 256, 0, stream>>>(x, g1, b1, wqkvT, b_qkv, wprojT, b_proj, out);
  // d_out += gelu(LN2(d_out) @ w_fc1 + b_fc1) @ w_fc2 + b_fc2   (in place)
  mlp_fused<<<4096, 256, 0, stream>>>(g2, b2, wfc1T, b_fc1, wfc2T, b_fc2, out);
}